// Round 1
// baseline (182.667 us; speedup 1.0000x reference)
//
#include <hip/hip_runtime.h>
#include <hip/hip_bf16.h>

#define BB   8
#define CIN  512
#define COUT 512
#define ZD   512
#define HH   64
#define WW   64

#define MOD_SCALE  0.04419417382415922f    // 1/sqrt(512)
#define CONV_SCALE 0.014731391274719742f   // 1/sqrt(512*9)

typedef __bf16 bf16x8 __attribute__((ext_vector_type(8)));
typedef float  f32x4  __attribute__((ext_vector_type(4)));

static __device__ __forceinline__ unsigned short f32_to_bf16_rne(float f) {
    unsigned int u = __float_as_uint(f);
    u = (u + 0x7FFFu + ((u >> 16) & 1u)) >> 16;
    return (unsigned short)u;
}

// ---------------- K0: s[b][i] = (style[b]·mod_w[i] * MOD_SCALE + mod_b[i]) * CONV_SCALE
__global__ void k_style(const float* __restrict__ style, const float* __restrict__ mod_w,
                        const float* __restrict__ mod_b, float* __restrict__ sconv) {
    int wid  = blockIdx.x * 4 + (threadIdx.x >> 6);   // 0..4095 = b*512+i
    int lane = threadIdx.x & 63;
    int b = wid >> 9;
    int i = wid & 511;
    const float4* st = (const float4*)(style + (size_t)b * ZD);
    const float4* mw = (const float4*)(mod_w + (size_t)i * ZD);
    float4 a0 = st[lane],      b0 = mw[lane];
    float4 a1 = st[lane + 64], b1 = mw[lane + 64];
    float sum = a0.x*b0.x + a0.y*b0.y + a0.z*b0.z + a0.w*b0.w
              + a1.x*b1.x + a1.y*b1.y + a1.z*b1.z + a1.w*b1.w;
    #pragma unroll
    for (int off = 32; off > 0; off >>= 1) sum += __shfl_down(sum, off);
    if (lane == 0) sconv[wid] = (sum * MOD_SCALE + mod_b[i]) * CONV_SCALE;
}

// ---------------- K1: xs2[b][h][w][i] = bf16(input[b][i][h][w] * sconv[b][i])  (NHWC, bf16)
__global__ void k_scale_input(const float* __restrict__ input, const float* __restrict__ sconv,
                              unsigned short* __restrict__ xs2) {
    int i0 = blockIdx.x * 32;
    int h  = blockIdx.y;
    int b  = blockIdx.z;
    __shared__ unsigned short lds[64][40];   // [w][ii], padded row
    #pragma unroll
    for (int r = 0; r < 8; ++r) {
        int ii = r * 4 + (threadIdx.x >> 6);
        int w  = threadIdx.x & 63;
        float v = input[(((size_t)b * CIN + i0 + ii) * HH + h) * WW + w];
        float s = sconv[b * CIN + i0 + ii];
        lds[w][ii] = f32_to_bf16_rne(v * s);
    }
    __syncthreads();
    int w = threadIdx.x >> 2, q = threadIdx.x & 3;
    int4 val = *(const int4*)&lds[w][q * 8];
    *(int4*)&xs2[(((size_t)b * HH + h) * WW + w) * CIN + i0 + q * 8] = val;
}

// ---------------- K2: w2[p][o][i] = bf16(weight[0][o][i][p])
__global__ void k_weight(const float* __restrict__ weight, unsigned short* __restrict__ w2) {
    int t = blockIdx.x * 256 + threadIdx.x;   // 0 .. 512*512-1
    int o = t >> 9, i = t & 511;
    const float* src = weight + ((size_t)o * CIN + i) * 9;
    #pragma unroll
    for (int p = 0; p < 9; ++p)
        w2[((size_t)p * COUT + o) * CIN + i] = f32_to_bf16_rne(src[p]);
}

// ---------------- K3: main conv. Block: 64 OC x (4 rows x 64 cols), 4 waves.
#define PADI 40   // LDS inner stride (bf16 elems): 80B -> 2-way bank aliasing (free)

__global__ __launch_bounds__(256, 2)
void k_conv(const unsigned short* __restrict__ xs2, const unsigned short* __restrict__ w2,
            float* __restrict__ out) {
    int y0  = blockIdx.x * 4;     // 16
    int oc0 = blockIdx.y * 64;    // 8
    int b   = blockIdx.z;         // 8
    int tid  = threadIdx.x;
    int wv   = tid >> 6;          // wave -> output row y0+wv
    int lane = tid & 63;
    int lm = lane & 15, hi = lane >> 4;

    __shared__ unsigned short lds_w[9 * 64 * PADI];   // [p*64+o][ii]
    __shared__ unsigned short lds_x[6 * 66 * PADI];   // [rr*66+xx][ii]; rr: y0-1.., xx: x+1

    f32x4 acc[4][4];
    #pragma unroll
    for (int mt = 0; mt < 4; ++mt)
        #pragma unroll
        for (int nt = 0; nt < 4; ++nt)
            acc[mt][nt] = (f32x4){0.f, 0.f, 0.f, 0.f};

    for (int ic = 0; ic < 16; ++ic) {
        int i0 = ic * 32;
        __syncthreads();
        // stage weights: 9*64*32 bf16 = 2304 x 16B, 9 per thread
        #pragma unroll
        for (int v = 0; v < 9; ++v) {
            int idx = v * 256 + tid;
            int po = idx >> 2;           // p*64+o
            int q  = idx & 3;
            int p = po >> 6, o = po & 63;
            int4 val = *(const int4*)&w2[((size_t)p * COUT + oc0 + o) * CIN + i0 + q * 8];
            *(int4*)&lds_w[po * PADI + q * 8] = val;
        }
        // stage input tile with halo: 6 rows x 66 cols x 32 ch = 1584 x 16B
        #pragma unroll
        for (int v = 0; v < 7; ++v) {
            int idx = v * 256 + tid;
            if (idx < 1584) {
                int pr = idx >> 2;       // rr*66+xx
                int q  = idx & 3;
                int rr = pr / 66, xx = pr - rr * 66;
                int hy = y0 - 1 + rr;
                int x  = xx - 1;
                int4 val = {0, 0, 0, 0};
                if ((unsigned)hy < 64u && (unsigned)x < 64u)
                    val = *(const int4*)&xs2[(((size_t)b * HH + hy) * WW + x) * CIN + i0 + q * 8];
                *(int4*)&lds_x[pr * PADI + q * 8] = val;
            }
        }
        __syncthreads();
        // compute: 9 taps x (4 a-frags + 4 b-frags + 16 MFMA)
        #pragma unroll
        for (int p = 0; p < 9; ++p) {
            int kh = p / 3, kw = p - kh * 3;
            bf16x8 afrag[4], bfrag[4];
            #pragma unroll
            for (int mt = 0; mt < 4; ++mt)
                afrag[mt] = *(const bf16x8*)&lds_w[(p * 64 + mt * 16 + lm) * PADI + 8 * hi];
            #pragma unroll
            for (int nt = 0; nt < 4; ++nt)
                bfrag[nt] = *(const bf16x8*)&lds_x[((wv + kh) * 66 + nt * 16 + lm + kw) * PADI + 8 * hi];
            #pragma unroll
            for (int mt = 0; mt < 4; ++mt)
                #pragma unroll
                for (int nt = 0; nt < 4; ++nt)
                    acc[mt][nt] = __builtin_amdgcn_mfma_f32_16x16x32_bf16(
                        afrag[mt], bfrag[nt], acc[mt][nt], 0, 0, 0);
        }
    }
    // epilogue: C/D layout col=lane&15, row=(lane>>4)*4+r   [m89/m91]
    int y = y0 + wv;
    #pragma unroll
    for (int mt = 0; mt < 4; ++mt)
        #pragma unroll
        for (int nt = 0; nt < 4; ++nt)
            #pragma unroll
            for (int r = 0; r < 4; ++r) {
                int oc = oc0 + mt * 16 + hi * 4 + r;
                out[(((size_t)b * COUT + oc) * HH + y) * WW + nt * 16 + lm] = acc[mt][nt][r];
            }
}

extern "C" void kernel_launch(void* const* d_in, const int* in_sizes, int n_in,
                              void* d_out, int out_size, void* d_ws, size_t ws_size,
                              hipStream_t stream) {
    const float* input  = (const float*)d_in[0];
    const float* style  = (const float*)d_in[1];
    const float* weight = (const float*)d_in[2];
    const float* mod_w  = (const float*)d_in[3];
    const float* mod_b  = (const float*)d_in[4];
    float* out = (float*)d_out;

    const size_t xs2_bytes = (size_t)BB * HH * WW * CIN * 2;     // 33.55 MB
    const size_t w2_bytes  = (size_t)9 * COUT * CIN * 2;         // 4.72 MB
    const size_t need = 16384 + xs2_bytes + w2_bytes;
    if (ws_size < need) return;   // insufficient scratch -> leave output poisoned (clear failure)

    float*          sconv = (float*)d_ws;
    unsigned short* xs2   = (unsigned short*)((char*)d_ws + 16384);
    unsigned short* w2    = (unsigned short*)((char*)d_ws + 16384 + xs2_bytes);

    hipLaunchKernelGGL(k_style,       dim3(1024),      dim3(256), 0, stream, style, mod_w, mod_b, sconv);
    hipLaunchKernelGGL(k_weight,      dim3(1024),      dim3(256), 0, stream, weight, w2);
    hipLaunchKernelGGL(k_scale_input, dim3(16, 64, 8), dim3(256), 0, stream, input, sconv, xs2);
    hipLaunchKernelGGL(k_conv,        dim3(16, 8, 8),  dim3(256), 0, stream, xs2, w2, out);
}

// Round 2
// 181.021 us; speedup vs baseline: 1.0091x; 1.0091x over previous
//
#include <hip/hip_runtime.h>
#include <hip/hip_bf16.h>

#define BB   8
#define CIN  512
#define COUT 512
#define ZD   512
#define HH   64
#define WW   64

#define MOD_SCALE  0.04419417382415922f    // 1/sqrt(512)
#define CONV_SCALE 0.014731391274719742f   // 1/sqrt(512*9)

typedef __bf16 bf16x8 __attribute__((ext_vector_type(8)));
typedef float  f32x4  __attribute__((ext_vector_type(4)));

static __device__ __forceinline__ unsigned short f32_to_bf16_rne(float f) {
    unsigned int u = __float_as_uint(f);
    u = (u + 0x7FFFu + ((u >> 16) & 1u)) >> 16;
    return (unsigned short)u;
}

// ---------------- K0: sconv[b][i] = (style[b]·mod_w[i]*MOD_SCALE + mod_b[i]) * CONV_SCALE
__global__ void k_style(const float* __restrict__ style, const float* __restrict__ mod_w,
                        const float* __restrict__ mod_b, float* __restrict__ sconv) {
    int wid  = blockIdx.x * 4 + (threadIdx.x >> 6);   // 0..4095 = b*512+i
    int lane = threadIdx.x & 63;
    int b = wid >> 9;
    int i = wid & 511;
    const float4* st = (const float4*)(style + (size_t)b * ZD);
    const float4* mw = (const float4*)(mod_w + (size_t)i * ZD);
    float4 a0 = st[lane],      b0 = mw[lane];
    float4 a1 = st[lane + 64], b1 = mw[lane + 64];
    float sum = a0.x*b0.x + a0.y*b0.y + a0.z*b0.z + a0.w*b0.w
              + a1.x*b1.x + a1.y*b1.y + a1.z*b1.z + a1.w*b1.w;
    #pragma unroll
    for (int off = 32; off > 0; off >>= 1) sum += __shfl_down(sum, off);
    if (lane == 0) sconv[wid] = (sum * MOD_SCALE + mod_b[i]) * CONV_SCALE;
}

// ---------------- K1: zero the 1-px border of padded xs2p [8][66][66][512] bf16
__global__ void k_zero_border(unsigned short* __restrict__ xs2p) {
    int b = blockIdx.y;
    int p = blockIdx.x * 4 + (threadIdx.x >> 6);   // 0..259
    int lane = threadIdx.x & 63;
    int h, w;
    if (p < 66)       { h = 0;       w = p; }
    else if (p < 132) { h = 65;      w = p - 66; }
    else if (p < 196) { h = p - 131; w = 0; }      // rows 1..64
    else              { h = p - 195; w = 65; }
    int4 z = {0, 0, 0, 0};
    *(int4*)&xs2p[((size_t)(b * 66 + h) * 66 + w) * 512 + lane * 8] = z;
}

// ---------------- K2: xs2p[b][h+1][w+1][i] = bf16(input[b][i][h][w] * sconv[b][i])
__global__ void k_scale_input(const float* __restrict__ input, const float* __restrict__ sconv,
                              unsigned short* __restrict__ xs2p) {
    int i0 = blockIdx.x * 32;
    int h  = blockIdx.y;
    int b  = blockIdx.z;
    __shared__ unsigned short lds[64][40];   // [w][ii], padded row
    #pragma unroll
    for (int r = 0; r < 8; ++r) {
        int ii = r * 4 + (threadIdx.x >> 6);
        int w  = threadIdx.x & 63;
        float v = input[(((size_t)b * CIN + i0 + ii) * HH + h) * WW + w];
        float s = sconv[b * CIN + i0 + ii];
        lds[w][ii] = f32_to_bf16_rne(v * s);
    }
    __syncthreads();
    int w = threadIdx.x >> 2, q = threadIdx.x & 3;
    int4 val = *(const int4*)&lds[w][q * 8];
    *(int4*)&xs2p[((size_t)(b * 66 + h + 1) * 66 + (w + 1)) * 512 + i0 + q * 8] = val;
}

// ---------------- K3: w2g granule-contiguous weights.
// granule idx = ((tap*16 + c)*4 + g)*512 + o ; holds ch [c*32+g*8, +8) of oc o, tap p.
__global__ void k_weight(const float* __restrict__ weight, unsigned short* __restrict__ w2g) {
    int t = blockIdx.x * 256 + threadIdx.x;   // 0 .. 512*512-1 : o*512 + i
    int o = t >> 9, i = t & 511;
    int c = i >> 5, g = (i >> 3) & 3, il = i & 7;
    const float* src = weight + ((size_t)o * CIN + i) * 9;
    #pragma unroll
    for (int p = 0; p < 9; ++p) {
        size_t gran = ((size_t)(p * 16 + c) * 4 + g) * 512 + o;
        w2g[gran * 8 + il] = f32_to_bf16_rne(src[p]);
    }
}

// ---------------- K4: main conv. 512 thr / 8 waves. Tile 256 OC x (4 rows x 64 cols).
// K-step = 1 tap x 32 ch (144 steps). LDS: 4 W-bufs (16KB) + 2 X-bufs (32KB) = 128KB.
#define WBOFF(j) ((j) * 16384)
#define XBOFF(j) (65536 + (j) * 32768)

#define GLD(srcp, ldsbyte)                                                        \
    __builtin_amdgcn_global_load_lds(                                             \
        (const __attribute__((address_space(1))) unsigned int*)(srcp),            \
        (__attribute__((address_space(3))) unsigned int*)(smb + (ldsbyte)),       \
        16, 0, 0)

__global__ __launch_bounds__(512, 2)
void k_conv(const unsigned short* __restrict__ xs2p, const unsigned short* __restrict__ w2g,
            float* __restrict__ out) {
    __shared__ unsigned short smem[65536];   // 131072 bytes
    char* smb = (char*)smem;

    const int tid  = threadIdx.x;
    const int wid  = tid >> 6, lane = tid & 63;
    const int wm   = wid >> 2, wr   = wid & 3;
    const int lm   = lane & 15, hi  = lane >> 4;
    const int oc0  = blockIdx.x * 256;
    const int y0   = blockIdx.y * 4;
    const int b    = blockIdx.z;

    // ---- staging source/dest precompute
    const int p_lin = wid * 64 + lane;               // 0..511
    const int xrow  = p_lin / 66;
    const int xcol  = p_lin - xrow * 66;
    const char* srcX = (const char*)xs2p;
    if (p_lin < 396)
        srcX += ((size_t)(b * 66 + y0 + xrow) * 66 + xcol) * 1024;  // 512ch*2B per pixel

    const int g0   = p_lin >> 8;                     // 0..1 (k=0); k=1 adds 2 planes
    const int oc_l = p_lin & 255;
    // W src: w2g byte addr = ((tap*16+c)*4)*512*16 + (g*512 + oc0 + oc_l)*16
    const char* pW = (const char*)w2g + ((size_t)g0 * 512 + oc0 + oc_l) * 16;

    const int wdst = wid * 1024 + (lane & 63) * 16;  // wave-linear LDS slice

    // ---- prologue: X(chunk0) + W(ts0) + W(ts1)
    #pragma unroll
    for (int k = 0; k < 4; ++k)
        GLD(srcX + k * 16, XBOFF(0) + k * 8192 + wdst);
    GLD(pW,                    WBOFF(0) + wdst);            // ts0 (tap0,c0) k=0
    GLD(pW + 16384,            WBOFF(0) + 8192 + wdst);     // k=1 (+2 planes)
    GLD(pW + 524288,           WBOFF(1) + wdst);            // ts1 (tap1)
    GLD(pW + 524288 + 16384,   WBOFF(1) + 8192 + wdst);
    pW += 2 * 524288;                                       // now points at ts+2 = 2
    asm volatile("s_waitcnt vmcnt(0)" ::: "memory");
    __builtin_amdgcn_s_barrier();

    f32x4 acc[8][4];
    #pragma unroll
    for (int mt = 0; mt < 8; ++mt)
        #pragma unroll
        for (int nt = 0; nt < 4; ++nt)
            acc[mt][nt] = (f32x4){0.f, 0.f, 0.f, 0.f};

    // lane-constant pieces of ds_read addresses
    const int aoff = hi * 4096 + (wm * 128 + lm) * 16;      // within W buf
    const int boff = hi * 8192 + (wr * 66 + lm) * 16;       // within X buf (before tap shift)

    int tap = 0, c = 0, tap2 = 2;
    bf16x8 afr[4], bfr[4];

    for (int ts = 0; ts < 144; ++ts) {
        const int wsel  = ts & 3;
        const int wsel2 = (ts + 2) & 3;
        const bool haveW2 = (ts <= 141);
        const int kh = tap / 3;
        const int kw = tap - kh * 3;
        const int ko = (kh * 66 + kw) * 16;

        const char* wbase = smb + WBOFF(wsel) + aoff;
        const char* xbase = smb + XBOFF(c & 1) + boff + ko;

        // ================= PHASE A =================
        if (haveW2) GLD(pW, WBOFF(wsel2) + wdst);
        if (tap == 0 && c < 15) {
            const char* sx = srcX + (c + 1) * 64;
            #pragma unroll
            for (int k = 0; k < 4; ++k)
                GLD(sx + k * 16, XBOFF((c + 1) & 1) + k * 8192 + wdst);
        }
        #pragma unroll
        for (int mt = 0; mt < 4; ++mt) afr[mt] = *(const bf16x8*)(wbase + mt * 256);
        #pragma unroll
        for (int nt = 0; nt < 4; ++nt) bfr[nt] = *(const bf16x8*)(xbase + nt * 256);
        __builtin_amdgcn_s_barrier();
        __builtin_amdgcn_s_setprio(1);
        #pragma unroll
        for (int mt = 0; mt < 4; ++mt)
            #pragma unroll
            for (int nt = 0; nt < 4; ++nt)
                acc[mt][nt] = __builtin_amdgcn_mfma_f32_16x16x32_bf16(
                    afr[mt], bfr[nt], acc[mt][nt], 0, 0, 0);
        __builtin_amdgcn_s_setprio(0);
        __builtin_amdgcn_s_barrier();

        // ================= PHASE B =================
        if (haveW2) GLD(pW + 16384, WBOFF(wsel2) + 8192 + wdst);
        #pragma unroll
        for (int mt = 0; mt < 4; ++mt) afr[mt] = *(const bf16x8*)(wbase + 1024 + mt * 256);
        __builtin_amdgcn_s_barrier();
        __builtin_amdgcn_s_setprio(1);
        #pragma unroll
        for (int mt = 0; mt < 4; ++mt)
            #pragma unroll
            for (int nt = 0; nt < 4; ++nt)
                acc[4 + mt][nt] = __builtin_amdgcn_mfma_f32_16x16x32_bf16(
                    afr[mt], bfr[nt], acc[4 + mt][nt], 0, 0, 0);
        __builtin_amdgcn_s_setprio(0);
        // derived wait: W(ts+1) (issued at ts-1) must be complete past this barrier.
        if (tap == 0 && c < 15)  { asm volatile("s_waitcnt vmcnt(6)" ::: "memory"); }
        else if (ts <= 141)      { asm volatile("s_waitcnt vmcnt(2)" ::: "memory"); }
        else                     { asm volatile("s_waitcnt vmcnt(0)" ::: "memory"); }
        __builtin_amdgcn_s_barrier();

        // advance counters / W source pointer (points at ts+3 now)
        if (haveW2) {
            ++tap2;
            if (tap2 == 9) { tap2 = 0; pW -= 127 * 32768; }  // tap 8->0, chunk+1
            else           { pW += 524288; }
        }
        ++tap;
        if (tap == 9) { tap = 0; ++c; }
    }

    // ---- epilogue: C/D layout col(n=pixel)=lane&15, row(m=oc)=(lane>>4)*4+r
    const int ybase = (y0 + wr) * 64;
    #pragma unroll
    for (int mt = 0; mt < 8; ++mt)
        #pragma unroll
        for (int nt = 0; nt < 4; ++nt)
            #pragma unroll
            for (int r = 0; r < 4; ++r) {
                int oc = oc0 + wm * 128 + mt * 16 + hi * 4 + r;
                out[((size_t)(b * COUT + oc) << 12) + ybase + nt * 16 + lm] = acc[mt][nt][r];
            }
}

extern "C" void kernel_launch(void* const* d_in, const int* in_sizes, int n_in,
                              void* d_out, int out_size, void* d_ws, size_t ws_size,
                              hipStream_t stream) {
    const float* input  = (const float*)d_in[0];
    const float* style  = (const float*)d_in[1];
    const float* weight = (const float*)d_in[2];
    const float* mod_w  = (const float*)d_in[3];
    const float* mod_b  = (const float*)d_in[4];
    float* out = (float*)d_out;

    const size_t xs2p_bytes = (size_t)BB * 66 * 66 * 512 * 2;   // 35,684,352
    const size_t w2_bytes   = (size_t)9 * 16 * 4 * 512 * 8 * 2; // 4,718,592
    const size_t need = 16384 + xs2p_bytes + w2_bytes;
    if (ws_size < need) return;   // leave output poisoned -> clear failure

    float*          sconv = (float*)d_ws;
    unsigned short* xs2p  = (unsigned short*)((char*)d_ws + 16384);
    unsigned short* w2g   = (unsigned short*)((char*)d_ws + 16384 + xs2p_bytes);

    hipLaunchKernelGGL(k_style,       dim3(1024),      dim3(256), 0, stream, style, mod_w, mod_b, sconv);
    hipLaunchKernelGGL(k_weight,      dim3(1024),      dim3(256), 0, stream, weight, w2g);
    hipLaunchKernelGGL(k_zero_border, dim3(65, 8),     dim3(256), 0, stream, xs2p);
    hipLaunchKernelGGL(k_scale_input, dim3(16, 64, 8), dim3(256), 0, stream, input, sconv, xs2p);
    hipLaunchKernelGGL(k_conv,        dim3(2, 16, 8),  dim3(512), 0, stream, xs2p, w2g, out);
}

// Round 3
// 157.344 us; speedup vs baseline: 1.1609x; 1.1505x over previous
//
#include <hip/hip_runtime.h>
#include <hip/hip_bf16.h>

#define BB   8
#define CIN  512
#define COUT 512
#define ZD   512
#define HH   64
#define WW   64

#define MOD_SCALE  0.04419417382415922f    // 1/sqrt(512)
#define CONV_SCALE 0.014731391274719742f   // 1/sqrt(512*9)

typedef __bf16 bf16x8 __attribute__((ext_vector_type(8)));
typedef float  f32x4  __attribute__((ext_vector_type(4)));

static __device__ __forceinline__ unsigned short f32_to_bf16_rne(float f) {
    unsigned int u = __float_as_uint(f);
    u = (u + 0x7FFFu + ((u >> 16) & 1u)) >> 16;
    return (unsigned short)u;
}

// ---------------- K0: sconv[b][i] = (style[b]·mod_w[i]*MOD_SCALE + mod_b[i]) * CONV_SCALE
__global__ void k_style(const float* __restrict__ style, const float* __restrict__ mod_w,
                        const float* __restrict__ mod_b, float* __restrict__ sconv) {
    int wid  = blockIdx.x * 4 + (threadIdx.x >> 6);   // 0..4095 = b*512+i
    int lane = threadIdx.x & 63;
    int b = wid >> 9;
    int i = wid & 511;
    const float4* st = (const float4*)(style + (size_t)b * ZD);
    const float4* mw = (const float4*)(mod_w + (size_t)i * ZD);
    float4 a0 = st[lane],      b0 = mw[lane];
    float4 a1 = st[lane + 64], b1 = mw[lane + 64];
    float sum = a0.x*b0.x + a0.y*b0.y + a0.z*b0.z + a0.w*b0.w
              + a1.x*b1.x + a1.y*b1.y + a1.z*b1.z + a1.w*b1.w;
    #pragma unroll
    for (int off = 32; off > 0; off >>= 1) sum += __shfl_down(sum, off);
    if (lane == 0) sconv[wid] = (sum * MOD_SCALE + mod_b[i]) * CONV_SCALE;
}

// ---------------- K1: zero the 1-px border of padded xs2p [8][66][66][512] bf16
__global__ void k_zero_border(unsigned short* __restrict__ xs2p) {
    int b = blockIdx.y;
    int p = blockIdx.x * 4 + (threadIdx.x >> 6);   // 0..259
    int lane = threadIdx.x & 63;
    int h, w;
    if (p < 66)       { h = 0;       w = p; }
    else if (p < 132) { h = 65;      w = p - 66; }
    else if (p < 196) { h = p - 131; w = 0; }      // rows 1..64
    else              { h = p - 195; w = 65; }
    int4 z = {0, 0, 0, 0};
    *(int4*)&xs2p[((size_t)(b * 66 + h) * 66 + w) * 512 + lane * 8] = z;
}

// ---------------- K2: xs2p[b][h+1][w+1][i] = bf16(input[b][i][h][w] * sconv[b][i])
__global__ void k_scale_input(const float* __restrict__ input, const float* __restrict__ sconv,
                              unsigned short* __restrict__ xs2p) {
    int i0 = blockIdx.x * 32;
    int h  = blockIdx.y;
    int b  = blockIdx.z;
    __shared__ unsigned short lds[64][40];   // [w][ii], padded row
    #pragma unroll
    for (int r = 0; r < 8; ++r) {
        int ii = r * 4 + (threadIdx.x >> 6);
        int w  = threadIdx.x & 63;
        float v = input[(((size_t)b * CIN + i0 + ii) * HH + h) * WW + w];
        float s = sconv[b * CIN + i0 + ii];
        lds[w][ii] = f32_to_bf16_rne(v * s);
    }
    __syncthreads();
    int w = threadIdx.x >> 2, q = threadIdx.x & 3;
    int4 val = *(const int4*)&lds[w][q * 8];
    *(int4*)&xs2p[((size_t)(b * 66 + h + 1) * 66 + (w + 1)) * 512 + i0 + q * 8] = val;
}

// ---------------- K3: w3 ts-linear weights. ts = c*9+tap.
// byte addr = ts*32768 + half*16384 + (g*256 + oc_low)*16 ; elem += i&7
__global__ void k_weight(const float* __restrict__ weight, unsigned short* __restrict__ w3) {
    int t = blockIdx.x * 256 + threadIdx.x;   // 0 .. 512*512-1 : o*512 + i
    int o = t >> 9, i = t & 511;
    int c = i >> 5, g = (i >> 3) & 3, il = i & 7;
    int h = o >> 8, ol = o & 255;
    const float* src = weight + ((size_t)o * CIN + i) * 9;
    #pragma unroll
    for (int p = 0; p < 9; ++p) {
        size_t gran = ((size_t)(c * 9 + p) * 2 + h) * 1024 + g * 256 + ol;
        w3[gran * 8 + il] = f32_to_bf16_rne(src[p]);
    }
}

// ---------------- K4: main conv. 512 thr / 8 waves. Tile 256 OC x (4 rows x 64 cols).
// ts = c*9+tap, 144 steps. LDS: W 4x16KB rotating (lead 3) + X 2x32KB = 128KB.
#define GLD(srcp, ldsbyte)                                                        \
    __builtin_amdgcn_global_load_lds(                                             \
        (const __attribute__((address_space(1))) unsigned int*)(srcp),            \
        (__attribute__((address_space(3))) unsigned int*)(smb + (ldsbyte)),       \
        16, 0, 0)

#define TAP(T, VMA, DOX, DOW) {                                                   \
    const int ko_ = ((T) / 3) * (66 * 16) + ((T) % 3) * 16;                       \
    const int wwr_ = (wrd + 49152) & 65535;                                       \
    if (DOW) GLD(pW, wwr_ + wdst);                                                \
    if ((DOX) && (T) == 0) GLD(sxn +  0, xwr + 0 * 8192 + wdst);                  \
    if ((DOX) && (T) == 1) GLD(sxn + 32, xwr + 2 * 8192 + wdst);                  \
    {   const char* wb = smb + wrd + aoff;                                        \
        const char* xb = smb + xrd + boff + ko_;                                  \
        _Pragma("unroll") for (int mt = 0; mt < 4; ++mt)                          \
            afr[mt] = *(const bf16x8*)(wb + mt * 256);                            \
        _Pragma("unroll") for (int nt = 0; nt < 4; ++nt)                          \
            bfr[nt] = *(const bf16x8*)(xb + nt * 256);                            \
    }                                                                             \
    __builtin_amdgcn_s_barrier();                                                 \
    __builtin_amdgcn_s_setprio(1);                                                \
    _Pragma("unroll") for (int mt = 0; mt < 4; ++mt)                              \
        _Pragma("unroll") for (int nt = 0; nt < 4; ++nt)                          \
            acc[mt][nt] = __builtin_amdgcn_mfma_f32_16x16x32_bf16(                \
                afr[mt], bfr[nt], acc[mt][nt], 0, 0, 0);                          \
    __builtin_amdgcn_s_setprio(0);                                                \
    __builtin_amdgcn_s_barrier();                                                 \
    if (DOW) GLD(pW + 8192, wwr_ + 8192 + wdst);                                  \
    if ((DOX) && (T) == 0) GLD(sxn + 16, xwr + 1 * 8192 + wdst);                  \
    if ((DOX) && (T) == 1) GLD(sxn + 48, xwr + 3 * 8192 + wdst);                  \
    {   const char* wb = smb + wrd + aoff + 1024;                                 \
        _Pragma("unroll") for (int mt = 0; mt < 4; ++mt)                          \
            afr[mt] = *(const bf16x8*)(wb + mt * 256);                            \
    }                                                                             \
    __builtin_amdgcn_s_barrier();                                                 \
    __builtin_amdgcn_s_setprio(1);                                                \
    _Pragma("unroll") for (int mt = 0; mt < 4; ++mt)                              \
        _Pragma("unroll") for (int nt = 0; nt < 4; ++nt)                          \
            acc[4 + mt][nt] = __builtin_amdgcn_mfma_f32_16x16x32_bf16(            \
                afr[mt], bfr[nt], acc[4 + mt][nt], 0, 0, 0);                      \
    __builtin_amdgcn_s_setprio(0);                                                \
    asm volatile("s_waitcnt vmcnt(" #VMA ")" ::: "memory");                       \
    __builtin_amdgcn_s_barrier();                                                 \
    wrd = (wrd + 16384) & 65535;                                                  \
    if (DOW) pW += 32768;                                                         \
}

__global__ __launch_bounds__(512, 2)
void k_conv(const unsigned short* __restrict__ xs2p, const unsigned short* __restrict__ w3,
            float* __restrict__ out) {
    __shared__ unsigned short smem[65536];   // 131072 bytes: W 0..64K, X 64K..128K
    char* smb = (char*)smem;

    const int tid  = threadIdx.x;
    const int wid  = tid >> 6, lane = tid & 63;
    const int wm   = wid >> 2, wr   = wid & 3;
    const int lm   = lane & 15, hi  = lane >> 4;
    const int half = blockIdx.x;              // 0,1 -> oc0 = half*256
    const int oc0  = half * 256;
    const int y0   = blockIdx.y * 4;
    const int b    = blockIdx.z;

    const int p_lin = wid * 64 + lane;               // 0..511
    const int xrow  = p_lin / 66;
    const int xcol  = p_lin - xrow * 66;
    const char* srcX = (const char*)xs2p;
    if (p_lin < 396)
        srcX += ((size_t)(b * 66 + y0 + xrow) * 66 + xcol) * 1024;  // 1KB per pixel

    const char* pW0 = (const char*)w3 + (size_t)half * 16384 + p_lin * 16;
    const int wdst = p_lin * 16;                     // wave-linear LDS slice

    // ---- prologue: X planes of chunk0, then W ts0,ts1,ts2 (FIFO order matters)
    GLD(srcX +  0, 65536 + 0 * 8192 + wdst);
    GLD(srcX + 16, 65536 + 1 * 8192 + wdst);
    GLD(srcX + 32, 65536 + 2 * 8192 + wdst);
    GLD(srcX + 48, 65536 + 3 * 8192 + wdst);
    GLD(pW0,          0     + wdst);
    GLD(pW0 +  8192,  8192  + wdst);
    GLD(pW0 + 32768,  16384 + wdst);
    GLD(pW0 + 40960,  24576 + wdst);
    GLD(pW0 + 65536,  32768 + wdst);
    GLD(pW0 + 73728,  40960 + wdst);
    const char* pW = pW0 + 3 * 32768;                // -> W(ts=3)
    asm volatile("s_waitcnt vmcnt(4)" ::: "memory"); // X + W0 landed; W1,W2 in flight
    __builtin_amdgcn_s_barrier();

    f32x4 acc[8][4];
    #pragma unroll
    for (int mt = 0; mt < 8; ++mt)
        #pragma unroll
        for (int nt = 0; nt < 4; ++nt)
            acc[mt][nt] = (f32x4){0.f, 0.f, 0.f, 0.f};

    const int aoff = hi * 4096 + (wm * 128 + lm) * 16;   // W frag base (bytes)
    const int boff = hi * 8192 + (wr * 66 + lm) * 16;    // X frag base (bytes)

    bf16x8 afr[4], bfr[4];
    int wrd = 0;             // W read buf = (ts&3)*16384
    int xrd = 65536;         // X read buf
    const char* sxn = srcX + 64;

    for (int c = 0; c < 15; ++c) {
        const int xwr = xrd ^ 32768;
        TAP(0, 6, 1, 1) TAP(1, 8, 1, 1) TAP(2, 7, 0, 1) TAP(3, 5, 0, 1)
        TAP(4, 4, 0, 1) TAP(5, 4, 0, 1) TAP(6, 4, 0, 1) TAP(7, 4, 0, 1)
        TAP(8, 4, 0, 1)
        sxn += 64; xrd ^= 32768;
    }
    {   // c = 15 tail: no X prefetch; last W issue at tap5 (ts=140 -> W143)
        const int xwr = 0; (void)xwr;
        TAP(0, 4, 0, 1) TAP(1, 4, 0, 1) TAP(2, 4, 0, 1) TAP(3, 4, 0, 1)
        TAP(4, 4, 0, 1) TAP(5, 4, 0, 1) TAP(6, 2, 0, 0) TAP(7, 0, 0, 0)
        TAP(8, 0, 0, 0)
    }

    // ---- epilogue: C/D layout col(n=pixel)=lane&15, row(m=oc)=(lane>>4)*4+r
    const int ybase = (y0 + wr) * 64;
    #pragma unroll
    for (int mt = 0; mt < 8; ++mt)
        #pragma unroll
        for (int nt = 0; nt < 4; ++nt)
            #pragma unroll
            for (int r = 0; r < 4; ++r) {
                int oc = oc0 + wm * 128 + mt * 16 + hi * 4 + r;
                out[((size_t)(b * COUT + oc) << 12) + ybase + nt * 16 + lm] = acc[mt][nt][r];
            }
}

extern "C" void kernel_launch(void* const* d_in, const int* in_sizes, int n_in,
                              void* d_out, int out_size, void* d_ws, size_t ws_size,
                              hipStream_t stream) {
    const float* input  = (const float*)d_in[0];
    const float* style  = (const float*)d_in[1];
    const float* weight = (const float*)d_in[2];
    const float* mod_w  = (const float*)d_in[3];
    const float* mod_b  = (const float*)d_in[4];
    float* out = (float*)d_out;

    const size_t xs2p_bytes = (size_t)BB * 66 * 66 * 512 * 2;   // 35,684,352
    const size_t w3_bytes   = (size_t)144 * 2 * 1024 * 8 * 2;   // 4,718,592
    const size_t need = 16384 + xs2p_bytes + w3_bytes;
    if (ws_size < need) return;   // leave output poisoned -> clear failure

    float*          sconv = (float*)d_ws;
    unsigned short* xs2p  = (unsigned short*)((char*)d_ws + 16384);
    unsigned short* w3    = (unsigned short*)((char*)d_ws + 16384 + xs2p_bytes);

    hipLaunchKernelGGL(k_style,       dim3(1024),      dim3(256), 0, stream, style, mod_w, mod_b, sconv);
    hipLaunchKernelGGL(k_weight,      dim3(1024),      dim3(256), 0, stream, weight, w3);
    hipLaunchKernelGGL(k_zero_border, dim3(65, 8),     dim3(256), 0, stream, xs2p);
    hipLaunchKernelGGL(k_scale_input, dim3(16, 64, 8), dim3(256), 0, stream, input, sconv, xs2p);
    hipLaunchKernelGGL(k_conv,        dim3(2, 16, 8),  dim3(512), 0, stream, xs2p, w3, out);
}